// Round 3
// baseline (36520.517 us; speedup 1.0000x reference)
//
#include <hip/hip_runtime.h>
#include <hip/hip_bf16.h>

#define NN 50000
#define TT 48
#define FIN 11
#define KH 288          // augmented K: 256 H + 11 X + 21 zero pad
#define BROWS 208       // rows per block; 241 blocks * 208 = 50128 >= 50000
#define GRID 241
// LDS layout (bytes)
#define XT_OFF 106496               // HT: 208 rows * 512 B (swizzled, pitch 256 bf16)
#define GB_OFF (106496 + 4992)      // XT: 208 * 24 B
#define SMEM_BYTES (GB_OFF + 32768) // GB: 64 rows * 512 B (rH / sigma(z) buffer) -> 144256 total

typedef __bf16 bf16_t;
typedef __bf16 v8bf __attribute__((ext_vector_type(8)));
typedef float v4f __attribute__((ext_vector_type(4)));

union U16 { uint4 q; v8bf v; uint2 d[2]; };

__device__ __forceinline__ float sigm(float x) { return 1.0f / (1.0f + __expf(-x)); }
__device__ __forceinline__ float tanhfast(float x) {
  float e = __expf(2.0f * x);
  return 1.0f - 2.0f / (e + 1.0f);
}

// XOR-swizzled LDS tile, pitch 256 bf16/row; 16B chunks XORed by (row&31).
__device__ __forceinline__ int sw_chunk(int row, int c) { return row * 256 + ((c ^ (row & 31)) << 3); }
__device__ __forceinline__ int sw_elem(int row, int k) {
  return row * 256 + ((((k >> 3) ^ (row & 31)) << 3) | (k & 7));
}
__device__ __forceinline__ v8bf ldtile(const bf16_t* T, int row, int kt, int quad) {
  U16 u; u.q = *(const uint4*)(T + sw_chunk(row, kt * 4 + quad)); return u.v;
}
// X-part of augmented K (kt==8): quad0 -> X cols 0..7, quad1 -> 8..11 (col11=0), quads 2,3 -> 0
__device__ __forceinline__ v8bf ldx(const bf16_t* XT, int row, int quad) {
  U16 u;
  u.d[0] = make_uint2(0u, 0u); u.d[1] = make_uint2(0u, 0u);
  if (quad == 0) { u.d[0] = *(const uint2*)(XT + row * 12); u.d[1] = *(const uint2*)(XT + row * 12 + 4); }
  else if (quad == 1) { u.d[0] = *(const uint2*)(XT + row * 12 + 8); }
  return u.v;
}
__device__ __forceinline__ v8bf ldg8(const bf16_t* p) {
  U16 u; u.q = *(const uint4*)p; return u.v;
}

// ---------------- weight/bias packing ----------------
// Bzr[512][288]: rows 0..255 [Wh0|Wx0|0] (z), rows 256..511 [Wh1|Wx1|0] (r)
// Bh [256][288]: [Wh2|Wx2|0]
// Bu [1024][256]: uWx g0 | uWx g2 | spWx g0 | spWx g2
// Bias[1792]: z | r | h | u0 | u2 | sp0 | sp2  (bx+bh combined)
__global__ void pack_w(const float* __restrict__ bbWx, const float* __restrict__ bbWh,
                       const float* __restrict__ uWx, const float* __restrict__ spWx,
                       const float* __restrict__ bbbx, const float* __restrict__ bbbh,
                       const float* __restrict__ ubx, const float* __restrict__ ubh,
                       const float* __restrict__ spbx, const float* __restrict__ spbh,
                       bf16_t* __restrict__ Bzr, bf16_t* __restrict__ Bh,
                       bf16_t* __restrict__ Bu, float* __restrict__ Bias) {
  int i0 = blockIdx.x * blockDim.x + threadIdx.x;
  int stride = gridDim.x * blockDim.x;
  for (int idx = i0; idx < 512 * KH; idx += stride) {
    int n = idx / KH, k = idx - n * KH;
    int g = n >> 8, nn = n & 255;
    float v = 0.0f;
    if (k < 256) v = bbWh[(g * 256 + nn) * 256 + k];
    else if (k < 256 + FIN) v = bbWx[(g * 256 + nn) * FIN + (k - 256)];
    Bzr[idx] = (bf16_t)v;
  }
  for (int idx = i0; idx < 256 * KH; idx += stride) {
    int n = idx / KH, k = idx - n * KH;
    float v = 0.0f;
    if (k < 256) v = bbWh[(512 + n) * 256 + k];
    else if (k < 256 + FIN) v = bbWx[(512 + n) * FIN + (k - 256)];
    Bh[idx] = (bf16_t)v;
  }
  for (int idx = i0; idx < 1024 * 256; idx += stride) {
    int n = idx >> 8, k = idx & 255;
    int g = n >> 8, nn = n & 255;
    const float* W = (g < 2) ? uWx : spWx;
    int gate = (g & 1) ? 2 : 0;
    Bu[idx] = (bf16_t)W[(gate * 256 + nn) * 256 + k];
  }
  for (int idx = i0; idx < 1792; idx += stride) {
    int seg = idx >> 8, j = idx & 255;
    float v;
    switch (seg) {
      case 0: v = bbbx[j] + bbbh[j]; break;
      case 1: v = bbbx[256 + j] + bbbh[256 + j]; break;
      case 2: v = bbbx[512 + j] + bbbh[512 + j]; break;
      case 3: v = ubx[j] + ubh[j]; break;
      case 4: v = ubx[512 + j] + ubh[512 + j]; break;
      case 5: v = spbx[j] + spbh[j]; break;
      default: v = spbx[512 + j] + spbh[512 + j]; break;
    }
    Bias[idx] = v;
  }
}

// out pre-initialized with biases; head partials atomicAdd on top.
__global__ void init_out(float* __restrict__ out, const float* __restrict__ buv,
                         const float* __restrict__ bsv, const float* __restrict__ bpv) {
  long i0 = (long)blockIdx.x * blockDim.x + threadIdx.x;
  long stride = (long)gridDim.x * blockDim.x;
  float b0 = buv[0], b1 = buv[1], b2 = buv[2], bs = bsv[0], bp = bpv[0];
  for (long i = i0; i < 12000000L; i += stride) {
    float v;
    if (i < 7200000L) { int k = (int)(i % 3); v = (k == 0) ? b0 : ((k == 1) ? b1 : b2); }
    else if (i < 9600000L) v = bs;
    else v = bp;
    out[i] = v;
  }
}

// ---------------- one 64-row (or 16-row tail) subtile, all phases ----------------
template <int SUBR>
__device__ __forceinline__ void do_subtile(
    int r0, bf16_t* __restrict__ HT, bf16_t* __restrict__ XT, bf16_t* __restrict__ GB,
    const bf16_t* __restrict__ Bzr, const bf16_t* __restrict__ Bh,
    const bf16_t* __restrict__ Bu, const float* __restrict__ Bias,
    const float* __restrict__ Wu, const float* __restrict__ Ws, const float* __restrict__ Wp,
    float* __restrict__ out, int t, long blockRow0,
    int w, int lane15, int quad) {
  constexpr int NROWG = (SUBR == 64) ? 2 : 1;
  constexpr int NSTRIP = 8 / NROWG;   // col strips across waves (A/B phases)
  constexpr int CW = 256 / NSTRIP;    // cols per strip
  constexpr int NF = CW / 16;
  constexpr int RG = SUBR / NROWG;    // rows per rowgroup
  constexpr int MF = RG / 16;
  constexpr int MFC = SUBR / 16;      // phase-C row fragments
  const int rowgrp = w / NSTRIP, strip = w % NSTRIP;
  const int rb = r0 + rowgrp * RG;    // HT row base (A/B)
  const int lrb = rowgrp * RG;        // GB-local row base

  // ===== phase A: r-gemm (K=288) =====
  v4f ar[MF][NF];
#pragma unroll
  for (int mf = 0; mf < MF; ++mf)
#pragma unroll
    for (int nf = 0; nf < NF; ++nf) ar[mf][nf] = v4f{0, 0, 0, 0};
  {
    const bf16_t* bp[NF];
#pragma unroll
    for (int nf = 0; nf < NF; ++nf)
      bp[nf] = Bzr + (long)(256 + strip * CW + nf * 16 + lane15) * KH + quad * 8;
    v8bf bc[NF], bn[NF];
#pragma unroll
    for (int nf = 0; nf < NF; ++nf) bc[nf] = ldg8(bp[nf]);
    for (int kt = 0; kt < 9; ++kt) {
      if (kt < 8) {
#pragma unroll
        for (int nf = 0; nf < NF; ++nf) bn[nf] = ldg8(bp[nf] + (kt + 1) * 32);
      }
      v8bf a[MF];
#pragma unroll
      for (int mf = 0; mf < MF; ++mf)
        a[mf] = (kt < 8) ? ldtile(HT, rb + mf * 16 + lane15, kt, quad)
                         : ldx(XT, rb + mf * 16 + lane15, quad);
#pragma unroll
      for (int mf = 0; mf < MF; ++mf)
#pragma unroll
        for (int nf = 0; nf < NF; ++nf)
          ar[mf][nf] = __builtin_amdgcn_mfma_f32_16x16x32_bf16(a[mf], bc[nf], ar[mf][nf], 0, 0, 0);
      if (kt < 8) {
#pragma unroll
        for (int nf = 0; nf < NF; ++nf) bc[nf] = bn[nf];
      }
    }
  }
  // epilogue: rH -> GB
#pragma unroll
  for (int nf = 0; nf < NF; ++nf) {
    const int col = strip * CW + nf * 16 + lane15;
    const float brv = Bias[256 + col];
#pragma unroll
    for (int mf = 0; mf < MF; ++mf)
#pragma unroll
      for (int rg = 0; rg < 4; ++rg) {
        const int lr = lrb + mf * 16 + quad * 4 + rg;
        const float rv = sigm(ar[mf][nf][rg] + brv);
        const float hp = (float)HT[sw_elem(r0 + lr, col)];
        GB[sw_elem(lr, col)] = (bf16_t)(rv * hp);
      }
  }
  __syncthreads();

  // ===== phase B: z-gemm (A=HT|X) + h-gemm (A=rH|X), same wave owns both =====
  v4f az[MF][NF], ah[MF][NF];
#pragma unroll
  for (int mf = 0; mf < MF; ++mf)
#pragma unroll
    for (int nf = 0; nf < NF; ++nf) { az[mf][nf] = v4f{0, 0, 0, 0}; ah[mf][nf] = v4f{0, 0, 0, 0}; }
  {
    const bf16_t* bzp[NF]; const bf16_t* bhp[NF];
#pragma unroll
    for (int nf = 0; nf < NF; ++nf) {
      const int col = strip * CW + nf * 16 + lane15;
      bzp[nf] = Bzr + (long)col * KH + quad * 8;
      bhp[nf] = Bh + (long)col * KH + quad * 8;
    }
    v8bf bzc[NF], bhc[NF], bzn[NF], bhn[NF];
#pragma unroll
    for (int nf = 0; nf < NF; ++nf) { bzc[nf] = ldg8(bzp[nf]); bhc[nf] = ldg8(bhp[nf]); }
    for (int kt = 0; kt < 9; ++kt) {
      if (kt < 8) {
#pragma unroll
        for (int nf = 0; nf < NF; ++nf) { bzn[nf] = ldg8(bzp[nf] + (kt + 1) * 32); bhn[nf] = ldg8(bhp[nf] + (kt + 1) * 32); }
      }
      v8bf aZ[MF], aH[MF];
#pragma unroll
      for (int mf = 0; mf < MF; ++mf) {
        if (kt < 8) {
          aZ[mf] = ldtile(HT, rb + mf * 16 + lane15, kt, quad);
          aH[mf] = ldtile(GB, lrb + mf * 16 + lane15, kt, quad);
        } else {
          aZ[mf] = ldx(XT, rb + mf * 16 + lane15, quad);
          aH[mf] = aZ[mf];
        }
      }
#pragma unroll
      for (int mf = 0; mf < MF; ++mf)
#pragma unroll
        for (int nf = 0; nf < NF; ++nf) {
          az[mf][nf] = __builtin_amdgcn_mfma_f32_16x16x32_bf16(aZ[mf], bzc[nf], az[mf][nf], 0, 0, 0);
          ah[mf][nf] = __builtin_amdgcn_mfma_f32_16x16x32_bf16(aH[mf], bhc[nf], ah[mf][nf], 0, 0, 0);
        }
      if (kt < 8) {
#pragma unroll
        for (int nf = 0; nf < NF; ++nf) { bzc[nf] = bzn[nf]; bhc[nf] = bhn[nf]; }
      }
    }
  }
  // epilogue: nonlinearities in-register, hp stashed in (free) ar, then barrier + HT update
#pragma unroll
  for (int nf = 0; nf < NF; ++nf) {
    const int col = strip * CW + nf * 16 + lane15;
    const float bzv = Bias[col], bhv = Bias[512 + col];
#pragma unroll
    for (int mf = 0; mf < MF; ++mf)
#pragma unroll
      for (int rg = 0; rg < 4; ++rg) {
        const int lr = lrb + mf * 16 + quad * 4 + rg;
        az[mf][nf][rg] = sigm(az[mf][nf][rg] + bzv);
        ah[mf][nf][rg] = tanhfast(ah[mf][nf][rg] + bhv);
        ar[mf][nf][rg] = (float)HT[sw_elem(r0 + lr, col)];  // hp
      }
  }
  __syncthreads();  // all A-reads of HT done before any update write
#pragma unroll
  for (int nf = 0; nf < NF; ++nf) {
    const int col = strip * CW + nf * 16 + lane15;
#pragma unroll
    for (int mf = 0; mf < MF; ++mf)
#pragma unroll
      for (int rg = 0; rg < 4; ++rg) {
        const int lr = lrb + mf * 16 + quad * 4 + rg;
        const float zz = az[mf][nf][rg];
        const float hn = zz * ar[mf][nf][rg] + (1.0f - zz) * ah[mf][nf][rg];
        HT[sw_elem(r0 + lr, col)] = (bf16_t)hn;
      }
  }
  __syncthreads();

  // ===== phase C: heads. wave: gate = w&1, jstrip = w>>1; two sequential GRU passes =====
  const int gate = w & 1, jstrip = w >> 1;
  const long SB = 7200000L, PB = 9600000L;
#pragma unroll
  for (int gru = 0; gru < 2; ++gru) {
    v4f ac[MFC][4];
#pragma unroll
    for (int mfc = 0; mfc < MFC; ++mfc)
#pragma unroll
      for (int nf = 0; nf < 4; ++nf) ac[mfc][nf] = v4f{0, 0, 0, 0};
    {
      const bf16_t* bp2[4];
#pragma unroll
      for (int nf = 0; nf < 4; ++nf)
        bp2[nf] = Bu + (long)(gru * 512 + gate * 256 + jstrip * 64 + nf * 16 + lane15) * 256 + quad * 8;
      v8bf bc2[4], bn2[4];
#pragma unroll
      for (int nf = 0; nf < 4; ++nf) bc2[nf] = ldg8(bp2[nf]);
      for (int kt = 0; kt < 8; ++kt) {
        if (kt < 7) {
#pragma unroll
          for (int nf = 0; nf < 4; ++nf) bn2[nf] = ldg8(bp2[nf] + (kt + 1) * 32);
        }
        v8bf a[MFC];
#pragma unroll
        for (int mfc = 0; mfc < MFC; ++mfc)
          a[mfc] = ldtile(HT, r0 + mfc * 16 + lane15, kt, quad);
#pragma unroll
        for (int mfc = 0; mfc < MFC; ++mfc)
#pragma unroll
          for (int nf = 0; nf < 4; ++nf)
            ac[mfc][nf] = __builtin_amdgcn_mfma_f32_16x16x32_bf16(a[mfc], bc2[nf], ac[mfc][nf], 0, 0, 0);
        if (kt < 7) {
#pragma unroll
          for (int nf = 0; nf < 4; ++nf) bc2[nf] = bn2[nf];
        }
      }
    }
    if (gate == 0) {  // sigma(z) -> GB
#pragma unroll
      for (int nf = 0; nf < 4; ++nf) {
        const int j = jstrip * 64 + nf * 16 + lane15;
        const float b0 = Bias[768 + gru * 512 + j];
#pragma unroll
        for (int mfc = 0; mfc < MFC; ++mfc)
#pragma unroll
          for (int rg = 0; rg < 4; ++rg) {
            const int lr = mfc * 16 + quad * 4 + rg;
            GB[sw_elem(lr, j)] = (bf16_t)sigm(ac[mfc][nf][rg] + b0);
          }
      }
    }
    __syncthreads();
    if (gate == 1) {  // hc = (1-z)*tanh(h); fused dots; shuffle-reduce; atomicAdd
      float p0[MFC][4], p1[MFC][4], p2[MFC][4];
#pragma unroll
      for (int mfc = 0; mfc < MFC; ++mfc)
#pragma unroll
        for (int rg = 0; rg < 4; ++rg) { p0[mfc][rg] = 0.0f; p1[mfc][rg] = 0.0f; p2[mfc][rg] = 0.0f; }
#pragma unroll
      for (int nf = 0; nf < 4; ++nf) {
        const int j = jstrip * 64 + nf * 16 + lane15;
        const float b1 = Bias[1024 + gru * 512 + j];
        const float w0 = gru ? Ws[j] : Wu[j];
        const float w1 = gru ? Wp[j] : Wu[256 + j];
        const float w2 = gru ? 0.0f : Wu[512 + j];
#pragma unroll
        for (int mfc = 0; mfc < MFC; ++mfc)
#pragma unroll
          for (int rg = 0; rg < 4; ++rg) {
            const int lr = mfc * 16 + quad * 4 + rg;
            const float sg = (float)GB[sw_elem(lr, j)];
            const float th = tanhfast(ac[mfc][nf][rg] + b1);
            const float hc = (1.0f - sg) * th;
            p0[mfc][rg] += hc * w0;
            p1[mfc][rg] += hc * w1;
            p2[mfc][rg] += hc * w2;
          }
      }
#pragma unroll
      for (int mfc = 0; mfc < MFC; ++mfc)
#pragma unroll
        for (int rg = 0; rg < 4; ++rg) {
          float v0 = p0[mfc][rg], v1 = p1[mfc][rg], v2 = p2[mfc][rg];
#pragma unroll
          for (int s = 1; s < 16; s <<= 1) {
            v0 += __shfl_xor(v0, s, 16);
            v1 += __shfl_xor(v1, s, 16);
            if (!gru) v2 += __shfl_xor(v2, s, 16);
          }
          const int lr = mfc * 16 + quad * 4 + rg;
          const long m = blockRow0 + r0 + lr;
          if (m < NN && lane15 < (gru ? 2 : 3)) {
            const float vv = (lane15 == 0) ? v0 : ((lane15 == 1) ? v1 : v2);
            if (!gru) atomicAdd(&out[(long)t * 150000 + m * 3 + lane15], vv);
            else atomicAdd(&out[(lane15 == 0 ? SB : PB) + (long)t * NN + m], vv);
          }
        }
    }
    __syncthreads();
  }
}

__global__ void __launch_bounds__(512, 2) fused_gru(
    const float* __restrict__ X,
    const bf16_t* __restrict__ Bzr, const bf16_t* __restrict__ Bh,
    const bf16_t* __restrict__ Bu, const float* __restrict__ Bias,
    const float* __restrict__ Wu, const float* __restrict__ Ws, const float* __restrict__ Wp,
    float* __restrict__ out) {
  extern __shared__ char smem[];
  bf16_t* HT = (bf16_t*)smem;
  bf16_t* XT = (bf16_t*)(smem + XT_OFF);
  bf16_t* GB = (bf16_t*)(smem + GB_OFF);
  const int tid = threadIdx.x;
  const int w = tid >> 6, lane15 = tid & 15, quad = (tid & 63) >> 4;
  const long blockRow0 = (long)blockIdx.x * BROWS;

  for (int i = tid; i < GB_OFF / 16; i += 512) ((uint4*)smem)[i] = make_uint4(0, 0, 0, 0);
  __syncthreads();
  for (int i = tid; i < BROWS * FIN; i += 512) {
    int r = i / FIN, f = i - r * FIN;
    long m = blockRow0 + r;
    float v = (m < NN) ? X[m * FIN + f] : 0.0f;
    XT[r * 12 + f] = (bf16_t)v;
  }
  __syncthreads();

  for (int t = 0; t < TT; ++t) {
    do_subtile<64>(0,   HT, XT, GB, Bzr, Bh, Bu, Bias, Wu, Ws, Wp, out, t, blockRow0, w, lane15, quad);
    do_subtile<64>(64,  HT, XT, GB, Bzr, Bh, Bu, Bias, Wu, Ws, Wp, out, t, blockRow0, w, lane15, quad);
    do_subtile<64>(128, HT, XT, GB, Bzr, Bh, Bu, Bias, Wu, Ws, Wp, out, t, blockRow0, w, lane15, quad);
    do_subtile<16>(192, HT, XT, GB, Bzr, Bh, Bu, Bias, Wu, Ws, Wp, out, t, blockRow0, w, lane15, quad);
    if (t + 1 < TT) {
      for (int i = tid; i < BROWS * FIN; i += 512) {
        int r = i / FIN, f = i - r * FIN;
        long m = blockRow0 + r;
        float v = (m < NN) ? X[((long)(t + 1) * NN + m) * FIN + f] : 0.0f;
        XT[r * 12 + f] = (bf16_t)v;
      }
    }
    __syncthreads();
  }
}

extern "C" void kernel_launch(void* const* d_in, const int* in_sizes, int n_in,
                              void* d_out, int out_size, void* d_ws, size_t ws_size,
                              hipStream_t stream) {
  const float* X    = (const float*)d_in[0];
  // d_in[1] edge_index unused (ChebConv K=1 ignores edges)
  const float* bbWx = (const float*)d_in[2];
  const float* bbbx = (const float*)d_in[3];
  const float* bbWh = (const float*)d_in[4];
  const float* bbbh = (const float*)d_in[5];
  const float* uWx  = (const float*)d_in[6];
  const float* ubx  = (const float*)d_in[7];
  const float* ubh  = (const float*)d_in[9];   // u_Wh (d_in[8]) dead: H=None
  const float* spWx = (const float*)d_in[10];
  const float* spbx = (const float*)d_in[11];
  const float* spbh = (const float*)d_in[13];  // sp_Wh (d_in[12]) dead
  const float* Wu   = (const float*)d_in[14];
  const float* buv  = (const float*)d_in[15];
  const float* Ws   = (const float*)d_in[16];
  const float* bsv  = (const float*)d_in[17];
  const float* Wp   = (const float*)d_in[18];
  const float* bpv  = (const float*)d_in[19];
  float* out = (float*)d_out;

  char* ws = (char*)d_ws;
  bf16_t* Bzr  = (bf16_t*)(ws);            // 512*288*2  = 294,912
  bf16_t* Bh   = (bf16_t*)(ws + 294912);   // 256*288*2  = 147,456
  bf16_t* Bu   = (bf16_t*)(ws + 442368);   // 1024*256*2 = 524,288
  float*  Bias = (float*)(ws + 966656);    // 1792*4     = 7,168
  if (ws_size < (size_t)(1 << 20)) return;

  hipFuncSetAttribute((const void*)fused_gru, hipFuncAttributeMaxDynamicSharedMemorySize,
                      SMEM_BYTES);

  pack_w<<<dim3(192), dim3(256), 0, stream>>>(bbWx, bbWh, uWx, spWx,
                                              bbbx, bbbh, ubx, ubh, spbx, spbh,
                                              Bzr, Bh, Bu, Bias);
  init_out<<<dim3(512), dim3(256), 0, stream>>>(out, buv, bsv, bpv);
  fused_gru<<<dim3(GRID), dim3(512), SMEM_BYTES, stream>>>(
      X, Bzr, Bh, Bu, Bias, Wu, Ws, Wp, out);
}

// Round 4
// 27368.405 us; speedup vs baseline: 1.3344x; 1.3344x over previous
//
#include <hip/hip_runtime.h>
#include <hip/hip_bf16.h>

#define NN 50000
#define TT 48
#define FIN 11
#define KH 288          // augmented K: 256 H + 11 X + 21 zero pad
#define GRID 241
#define BROWS 208       // 241 * 208 = 50128 >= 50000
// LDS layout (bytes)
#define XT_OFF 106496               // HT: 208 rows * 512 B (swizzled, pitch 256 bf16)
#define GB_OFF 111488               // XT: 208 * 12 bf16 = 4992 B
#define SMEM_BYTES 144256           // GB: 64 rows * 512 B (rH / h~ / head partials)
#define SB_OFF 7200000L
#define PB_OFF 9600000L

typedef __bf16 bf16_t;
typedef __bf16 v8bf __attribute__((ext_vector_type(8)));
typedef float v4f __attribute__((ext_vector_type(4)));

union U16 { uint4 q; v8bf v; uint2 d[2]; };

__device__ __forceinline__ float sigm(float x) { return 1.0f / (1.0f + __expf(-x)); }
__device__ __forceinline__ float tanhfast(float x) {
  float e = __expf(2.0f * x);
  return 1.0f - 2.0f / (e + 1.0f);
}

// XOR-swizzled LDS tile, pitch 256 bf16/row; 16B chunks XORed by (row&31).
__device__ __forceinline__ int sw_chunk(int row, int c) { return row * 256 + ((c ^ (row & 31)) << 3); }
__device__ __forceinline__ int sw_elem(int row, int k) {
  return row * 256 + ((((k >> 3) ^ (row & 31)) << 3) | (k & 7));
}
__device__ __forceinline__ v8bf ldtile(const bf16_t* T, int row, int kt, int quad) {
  U16 u; u.q = *(const uint4*)(T + sw_chunk(row, kt * 4 + quad)); return u.v;
}
// X-part of augmented K (kt==8): quad0 -> X cols 0..7, quad1 -> 8..11 (col11=0), quads 2,3 -> 0
__device__ __forceinline__ v8bf ldx(const bf16_t* XT, int row, int quad) {
  U16 u;
  u.d[0] = make_uint2(0u, 0u); u.d[1] = make_uint2(0u, 0u);
  if (quad == 0) { u.d[0] = *(const uint2*)(XT + row * 12); u.d[1] = *(const uint2*)(XT + row * 12 + 4); }
  else if (quad == 1) { u.d[0] = *(const uint2*)(XT + row * 12 + 8); }
  return u.v;
}
__device__ __forceinline__ v8bf ldg8(const bf16_t* p) {
  U16 u; u.q = *(const uint4*)p; return u.v;
}

// Perf-only grid barrier: bounded spin, never deadlocks; correctness does not
// depend on it (weights are read-only, outputs disjoint). Keeps all 241
// co-resident blocks step-locked so the ~1MB weight set stays hot in L2.
__device__ __forceinline__ void grid_barrier(unsigned* cnt, unsigned target, int tid) {
  __syncthreads();
  if (tid == 0) {
    atomicAdd(cnt, 1u);
    int polls = 0;
    while (__hip_atomic_load(cnt, __ATOMIC_RELAXED, __HIP_MEMORY_SCOPE_AGENT) < target) {
      if (++polls > 20000) break;
      __builtin_amdgcn_s_sleep(8);
    }
  }
  __syncthreads();
}

// ---------------- weight/bias packing ----------------
// Bzr[512][288]: rows 0..255 [Wh0|Wx0|0] (z), rows 256..511 [Wh1|Wx1|0] (r)
// Bh [256][288]: [Wh2|Wx2|0]
// Bu [1024][256]: uWx g0 | uWx g2 | spWx g0 | spWx g2
// Bias[1792]: z | r | h | u0 | u2 | sp0 | sp2  (bx+bh combined)
__global__ void pack_w(const float* __restrict__ bbWx, const float* __restrict__ bbWh,
                       const float* __restrict__ uWx, const float* __restrict__ spWx,
                       const float* __restrict__ bbbx, const float* __restrict__ bbbh,
                       const float* __restrict__ ubx, const float* __restrict__ ubh,
                       const float* __restrict__ spbx, const float* __restrict__ spbh,
                       bf16_t* __restrict__ Bzr, bf16_t* __restrict__ Bh,
                       bf16_t* __restrict__ Bu, float* __restrict__ Bias,
                       unsigned* __restrict__ barcnt) {
  int i0 = blockIdx.x * blockDim.x + threadIdx.x;
  int stride = gridDim.x * blockDim.x;
  if (i0 == 0) *barcnt = 0u;
  for (int idx = i0; idx < 512 * KH; idx += stride) {
    int n = idx / KH, k = idx - n * KH;
    int g = n >> 8, nn = n & 255;
    float v = 0.0f;
    if (k < 256) v = bbWh[(g * 256 + nn) * 256 + k];
    else if (k < 256 + FIN) v = bbWx[(g * 256 + nn) * FIN + (k - 256)];
    Bzr[idx] = (bf16_t)v;
  }
  for (int idx = i0; idx < 256 * KH; idx += stride) {
    int n = idx / KH, k = idx - n * KH;
    float v = 0.0f;
    if (k < 256) v = bbWh[(512 + n) * 256 + k];
    else if (k < 256 + FIN) v = bbWx[(512 + n) * FIN + (k - 256)];
    Bh[idx] = (bf16_t)v;
  }
  for (int idx = i0; idx < 1024 * 256; idx += stride) {
    int n = idx >> 8, k = idx & 255;
    int g = n >> 8, nn = n & 255;
    const float* W = (g < 2) ? uWx : spWx;
    int gate = (g & 1) ? 2 : 0;
    Bu[idx] = (bf16_t)W[(gate * 256 + nn) * 256 + k];
  }
  for (int idx = i0; idx < 1792; idx += stride) {
    int seg = idx >> 8, j = idx & 255;
    float v;
    switch (seg) {
      case 0: v = bbbx[j] + bbbh[j]; break;
      case 1: v = bbbx[256 + j] + bbbh[256 + j]; break;
      case 2: v = bbbx[512 + j] + bbbh[512 + j]; break;
      case 3: v = ubx[j] + ubh[j]; break;
      case 4: v = ubx[512 + j] + ubh[512 + j]; break;
      case 5: v = spbx[j] + spbh[j]; break;
      default: v = spbx[512 + j] + spbh[512 + j]; break;
    }
    Bias[idx] = v;
  }
}

// ---------------- one subtile (64 or 16 rows), all phases ----------------
// Register budget per wave (by design, to stay spill-free under the 256 cap):
//   A: acc 32 | B: acc 64 + bfrag 32 + a 16 | C: acc 64 + bfrag 32 + partials 48
template <int SUBR>
__device__ __forceinline__ void do_subtile(
    int r0, bf16_t* __restrict__ HT, bf16_t* __restrict__ XT, bf16_t* __restrict__ GB,
    const bf16_t* __restrict__ Bzr, const bf16_t* __restrict__ Bh,
    const bf16_t* __restrict__ Bu, const float* __restrict__ Bias,
    const float* __restrict__ Wu, const float* __restrict__ Ws, const float* __restrict__ Wp,
    const float* __restrict__ buv, const float* __restrict__ bsv, const float* __restrict__ bpv,
    float* __restrict__ out, int t, long blockRow0,
    int w, int lane15, int quad, int tid) {
  // ===== phase A: r-gemm (K=288). 8 waves x (32rows x 64cols) [64] or (16x32) [16] =====
  {
    constexpr int AMF = (SUBR == 64) ? 2 : 1;
    constexpr int ANF = (SUBR == 64) ? 4 : 2;
    const int alr0 = (SUBR == 64) ? ((w >> 2) * 32) : 0;
    const int astrip = (SUBR == 64) ? ((w & 3) * 64) : (w * 32);
    v4f ar[AMF][ANF];
#pragma unroll
    for (int mf = 0; mf < AMF; ++mf)
#pragma unroll
      for (int nf = 0; nf < ANF; ++nf) ar[mf][nf] = v4f{0, 0, 0, 0};
    const bf16_t* bp[ANF];
#pragma unroll
    for (int nf = 0; nf < ANF; ++nf)
      bp[nf] = Bzr + (long)(256 + astrip + nf * 16 + lane15) * KH + quad * 8;
    v8bf bc[ANF], bn[ANF];
#pragma unroll
    for (int nf = 0; nf < ANF; ++nf) bc[nf] = ldg8(bp[nf]);
    for (int kt = 0; kt < 9; ++kt) {
      if (kt < 8) {
#pragma unroll
        for (int nf = 0; nf < ANF; ++nf) bn[nf] = ldg8(bp[nf] + (kt + 1) * 32);
      }
      v8bf a[AMF];
#pragma unroll
      for (int mf = 0; mf < AMF; ++mf) {
        const int row = r0 + alr0 + mf * 16 + lane15;
        a[mf] = (kt < 8) ? ldtile(HT, row, kt, quad) : ldx(XT, row, quad);
      }
#pragma unroll
      for (int mf = 0; mf < AMF; ++mf)
#pragma unroll
        for (int nf = 0; nf < ANF; ++nf)
          ar[mf][nf] = __builtin_amdgcn_mfma_f32_16x16x32_bf16(a[mf], bc[nf], ar[mf][nf], 0, 0, 0);
      if (kt < 8) {
#pragma unroll
        for (int nf = 0; nf < ANF; ++nf) bc[nf] = bn[nf];
      }
    }
    // epilogue: rH = sigm(r)*Hprev -> GB
#pragma unroll
    for (int nf = 0; nf < ANF; ++nf) {
      const int col = astrip + nf * 16 + lane15;
      const float brv = Bias[256 + col];
#pragma unroll
      for (int mf = 0; mf < AMF; ++mf)
#pragma unroll
        for (int rg = 0; rg < 4; ++rg) {
          const int lr = alr0 + mf * 16 + quad * 4 + rg;
          const float rv = sigm(ar[mf][nf][rg] + brv);
          const float hp = (float)HT[sw_elem(r0 + lr, col)];
          GB[sw_elem(lr, col)] = (bf16_t)(rv * hp);
        }
    }
  }
  __syncthreads();

  // ===== phase B: waves 0-3 z-gemm (A=HT|X), waves 4-7 h-gemm (A=rH|X) =====
  {
    constexpr int BMF = SUBR / 16;
    const int role = w >> 2;  // 0=z, 1=h~
    const int bstrip = (w & 3) * 64;
    v4f ac[BMF][4];
#pragma unroll
    for (int mf = 0; mf < BMF; ++mf)
#pragma unroll
      for (int nf = 0; nf < 4; ++nf) ac[mf][nf] = v4f{0, 0, 0, 0};
    const bf16_t* wmat = role ? Bh : Bzr;
    const bf16_t* bp[4];
#pragma unroll
    for (int nf = 0; nf < 4; ++nf)
      bp[nf] = wmat + (long)(bstrip + nf * 16 + lane15) * KH + quad * 8;
    v8bf bc[4], bn[4];
#pragma unroll
    for (int nf = 0; nf < 4; ++nf) bc[nf] = ldg8(bp[nf]);
    for (int kt = 0; kt < 9; ++kt) {
      if (kt < 8) {
#pragma unroll
        for (int nf = 0; nf < 4; ++nf) bn[nf] = ldg8(bp[nf] + (kt + 1) * 32);
      }
      v8bf a[BMF];
#pragma unroll
      for (int mf = 0; mf < BMF; ++mf) {
        const int rr = mf * 16 + lane15;
        if (kt < 8) a[mf] = role ? ldtile(GB, rr, kt, quad) : ldtile(HT, r0 + rr, kt, quad);
        else a[mf] = ldx(XT, r0 + rr, quad);
      }
#pragma unroll
      for (int mf = 0; mf < BMF; ++mf)
#pragma unroll
        for (int nf = 0; nf < 4; ++nf)
          ac[mf][nf] = __builtin_amdgcn_mfma_f32_16x16x32_bf16(a[mf], bc[nf], ac[mf][nf], 0, 0, 0);
      if (kt < 8) {
#pragma unroll
        for (int nf = 0; nf < 4; ++nf) bc[nf] = bn[nf];
      }
    }
    // nonlinearity in registers
#pragma unroll
    for (int nf = 0; nf < 4; ++nf) {
      const int col = bstrip + nf * 16 + lane15;
      const float bz = Bias[col], bh = Bias[512 + col];
#pragma unroll
      for (int mf = 0; mf < BMF; ++mf)
#pragma unroll
        for (int rg = 0; rg < 4; ++rg) {
          const float v = ac[mf][nf][rg];
          ac[mf][nf][rg] = role ? tanhfast(v + bh) : sigm(v + bz);
        }
    }
    __syncthreads();  // all gemm reads of GB(rH)/HT done
    if (role == 1) {  // write h~ into GB (overwrites consumed rH)
#pragma unroll
      for (int nf = 0; nf < 4; ++nf) {
        const int col = bstrip + nf * 16 + lane15;
#pragma unroll
        for (int mf = 0; mf < BMF; ++mf)
#pragma unroll
          for (int rg = 0; rg < 4; ++rg) {
            const int lr = mf * 16 + quad * 4 + rg;
            GB[sw_elem(lr, col)] = (bf16_t)ac[mf][nf][rg];
          }
      }
    }
    __syncthreads();
    if (role == 0) {  // H update: z*hp + (1-z)*h~
#pragma unroll
      for (int nf = 0; nf < 4; ++nf) {
        const int col = bstrip + nf * 16 + lane15;
#pragma unroll
        for (int mf = 0; mf < BMF; ++mf)
#pragma unroll
          for (int rg = 0; rg < 4; ++rg) {
            const int lr = mf * 16 + quad * 4 + rg;
            const float zz = ac[mf][nf][rg];
            const float hp = (float)HT[sw_elem(r0 + lr, col)];
            const float ht = (float)GB[sw_elem(lr, col)];
            HT[sw_elem(r0 + lr, col)] = (bf16_t)(zz * hp + (1.0f - zz) * ht);
          }
      }
    }
    __syncthreads();
  }

  // ===== phase C: heads. 8 waves x 32-col strips, both gates per wave =====
  {
    constexpr int CMF = SUBR / 16;
    float* GBf = (float*)GB;  // partials: [row][slot 0..4][wave 0..7] = SUBR*40 floats
#pragma unroll
    for (int gru = 0; gru < 2; ++gru) {  // 0: gru_u (3 dots), 1: gru_sp (S,P)
      v4f az[CMF][2], ah[CMF][2];
#pragma unroll
      for (int mf = 0; mf < CMF; ++mf)
#pragma unroll
        for (int nf = 0; nf < 2; ++nf) { az[mf][nf] = v4f{0, 0, 0, 0}; ah[mf][nf] = v4f{0, 0, 0, 0}; }
      const bf16_t* zp[2]; const bf16_t* hp2[2];
#pragma unroll
      for (int nf = 0; nf < 2; ++nf) {
        const int j = w * 32 + nf * 16 + lane15;
        zp[nf] = Bu + (long)(gru * 512 + j) * 256 + quad * 8;
        hp2[nf] = Bu + (long)(gru * 512 + 256 + j) * 256 + quad * 8;
      }
      v8bf bzc[2], bhc[2], bzn[2], bhn[2];
#pragma unroll
      for (int nf = 0; nf < 2; ++nf) { bzc[nf] = ldg8(zp[nf]); bhc[nf] = ldg8(hp2[nf]); }
      for (int kt = 0; kt < 8; ++kt) {
        if (kt < 7) {
#pragma unroll
          for (int nf = 0; nf < 2; ++nf) { bzn[nf] = ldg8(zp[nf] + (kt + 1) * 32); bhn[nf] = ldg8(hp2[nf] + (kt + 1) * 32); }
        }
        v8bf a[CMF];
#pragma unroll
        for (int mf = 0; mf < CMF; ++mf)
          a[mf] = ldtile(HT, r0 + mf * 16 + lane15, kt, quad);
#pragma unroll
        for (int mf = 0; mf < CMF; ++mf)
#pragma unroll
          for (int nf = 0; nf < 2; ++nf) {
            az[mf][nf] = __builtin_amdgcn_mfma_f32_16x16x32_bf16(a[mf], bzc[nf], az[mf][nf], 0, 0, 0);
            ah[mf][nf] = __builtin_amdgcn_mfma_f32_16x16x32_bf16(a[mf], bhc[nf], ah[mf][nf], 0, 0, 0);
          }
        if (kt < 7) {
#pragma unroll
          for (int nf = 0; nf < 2; ++nf) { bzc[nf] = bzn[nf]; bhc[nf] = bhn[nf]; }
        }
      }
      // fused nonlinearity + head dots
      float p0[CMF][4], p1[CMF][4], p2[CMF][4];
#pragma unroll
      for (int mf = 0; mf < CMF; ++mf)
#pragma unroll
        for (int rg = 0; rg < 4; ++rg) { p0[mf][rg] = 0.0f; p1[mf][rg] = 0.0f; p2[mf][rg] = 0.0f; }
#pragma unroll
      for (int nf = 0; nf < 2; ++nf) {
        const int j = w * 32 + nf * 16 + lane15;
        const float g0 = Bias[768 + gru * 512 + j];
        const float g2 = Bias[1024 + gru * 512 + j];
        const float w0 = gru ? Ws[j] : Wu[j];
        const float w1 = gru ? Wp[j] : Wu[256 + j];
        const float w2 = gru ? 0.0f : Wu[512 + j];
#pragma unroll
        for (int mf = 0; mf < CMF; ++mf)
#pragma unroll
          for (int rg = 0; rg < 4; ++rg) {
            const float zz = sigm(az[mf][nf][rg] + g0);
            const float th = tanhfast(ah[mf][nf][rg] + g2);
            const float hc = (1.0f - zz) * th;  // hu = (1-z)*h~ since Hprev=0
            p0[mf][rg] += hc * w0;
            p1[mf][rg] += hc * w1;
            p2[mf][rg] += hc * w2;
          }
      }
      // reduce over lane15 (j within strip), stash per-wave partials
#pragma unroll
      for (int mf = 0; mf < CMF; ++mf)
#pragma unroll
        for (int rg = 0; rg < 4; ++rg) {
          float v0 = p0[mf][rg], v1 = p1[mf][rg], v2 = p2[mf][rg];
#pragma unroll
          for (int s = 1; s < 16; s <<= 1) {
            v0 += __shfl_xor(v0, s, 16);
            v1 += __shfl_xor(v1, s, 16);
            if (!gru) v2 += __shfl_xor(v2, s, 16);
          }
          const int lr = mf * 16 + quad * 4 + rg;
          if (!gru) {
            if (lane15 < 3) {
              const float vv = (lane15 == 0) ? v0 : ((lane15 == 1) ? v1 : v2);
              GBf[lr * 40 + lane15 * 8 + w] = vv;
            }
          } else {
            if (lane15 < 2) GBf[lr * 40 + (3 + lane15) * 8 + w] = lane15 ? v1 : v0;
          }
        }
      __syncthreads();
      // combine 8 wave partials, add bias, store
      if (!gru) {
        for (int o = tid; o < SUBR * 3; o += 512) {
          const int row = o / 3, k = o - row * 3;
          const long m = blockRow0 + r0 + row;
          if (m < NN) {
            float s = 0.0f;
#pragma unroll
            for (int ww = 0; ww < 8; ++ww) s += GBf[row * 40 + k * 8 + ww];
            out[(long)t * 150000 + m * 3 + k] = s + buv[k];
          }
        }
      } else {
        for (int o = tid; o < SUBR * 2; o += 512) {
          const int row = o >> 1, which = o & 1;
          const long m = blockRow0 + r0 + row;
          if (m < NN) {
            float s = 0.0f;
#pragma unroll
            for (int ww = 0; ww < 8; ++ww) s += GBf[row * 40 + (3 + which) * 8 + ww];
            out[(which ? PB_OFF : SB_OFF) + (long)t * NN + m] = s + (which ? bpv[0] : bsv[0]);
          }
        }
      }
      __syncthreads();
    }
  }
}

__global__ void __launch_bounds__(512, 1) fused_gru(
    const float* __restrict__ X,
    const bf16_t* __restrict__ Bzr, const bf16_t* __restrict__ Bh,
    const bf16_t* __restrict__ Bu, const float* __restrict__ Bias,
    const float* __restrict__ Wu, const float* __restrict__ Ws, const float* __restrict__ Wp,
    const float* __restrict__ buv, const float* __restrict__ bsv, const float* __restrict__ bpv,
    float* __restrict__ out, unsigned* __restrict__ barcnt) {
  extern __shared__ char smem[];
  bf16_t* HT = (bf16_t*)smem;
  bf16_t* XT = (bf16_t*)(smem + XT_OFF);
  bf16_t* GB = (bf16_t*)(smem + GB_OFF);
  const int tid = threadIdx.x;
  const int w = tid >> 6, lane15 = tid & 15, quad = (tid & 63) >> 4;
  const long blockRow0 = (long)blockIdx.x * BROWS;

  // zero HT + XT
  for (int i = tid; i < GB_OFF / 16; i += 512) ((uint4*)smem)[i] = make_uint4(0, 0, 0, 0);
  __syncthreads();
  // stage X_0
  for (int i = tid; i < BROWS * FIN; i += 512) {
    int r = i / FIN, f = i - r * FIN;
    long m = blockRow0 + r;
    float v = (m < NN) ? X[m * FIN + f] : 0.0f;
    XT[r * 12 + f] = (bf16_t)v;
  }
  __syncthreads();

  for (int t = 0; t < TT; ++t) {
    do_subtile<64>(0,   HT, XT, GB, Bzr, Bh, Bu, Bias, Wu, Ws, Wp, buv, bsv, bpv, out, t, blockRow0, w, lane15, quad, tid);
    do_subtile<64>(64,  HT, XT, GB, Bzr, Bh, Bu, Bias, Wu, Ws, Wp, buv, bsv, bpv, out, t, blockRow0, w, lane15, quad, tid);
    do_subtile<64>(128, HT, XT, GB, Bzr, Bh, Bu, Bias, Wu, Ws, Wp, buv, bsv, bpv, out, t, blockRow0, w, lane15, quad, tid);
    do_subtile<16>(192, HT, XT, GB, Bzr, Bh, Bu, Bias, Wu, Ws, Wp, buv, bsv, bpv, out, t, blockRow0, w, lane15, quad, tid);
    if (t + 1 < TT) {
      for (int i = tid; i < BROWS * FIN; i += 512) {
        int r = i / FIN, f = i - r * FIN;
        long m = blockRow0 + r;
        float v = (m < NN) ? X[((long)(t + 1) * NN + m) * FIN + f] : 0.0f;
        XT[r * 12 + f] = (bf16_t)v;
      }
      __syncthreads();
      grid_barrier(barcnt, (unsigned)GRID * (unsigned)(t + 1), tid);
    }
  }
}

extern "C" void kernel_launch(void* const* d_in, const int* in_sizes, int n_in,
                              void* d_out, int out_size, void* d_ws, size_t ws_size,
                              hipStream_t stream) {
  const float* X    = (const float*)d_in[0];
  // d_in[1] edge_index unused (ChebConv K=1 ignores edges)
  const float* bbWx = (const float*)d_in[2];
  const float* bbbx = (const float*)d_in[3];
  const float* bbWh = (const float*)d_in[4];
  const float* bbbh = (const float*)d_in[5];
  const float* uWx  = (const float*)d_in[6];
  const float* ubx  = (const float*)d_in[7];
  const float* ubh  = (const float*)d_in[9];   // u_Wh (d_in[8]) dead: H=None
  const float* spWx = (const float*)d_in[10];
  const float* spbx = (const float*)d_in[11];
  const float* spbh = (const float*)d_in[13];  // sp_Wh (d_in[12]) dead
  const float* Wu   = (const float*)d_in[14];
  const float* buv  = (const float*)d_in[15];
  const float* Ws   = (const float*)d_in[16];
  const float* bsv  = (const float*)d_in[17];
  const float* Wp   = (const float*)d_in[18];
  const float* bpv  = (const float*)d_in[19];
  float* out = (float*)d_out;

  char* ws = (char*)d_ws;
  bf16_t* Bzr    = (bf16_t*)(ws);            // 512*288*2  = 294,912
  bf16_t* Bh     = (bf16_t*)(ws + 294912);   // 256*288*2  = 147,456
  bf16_t* Bu     = (bf16_t*)(ws + 442368);   // 1024*256*2 = 524,288
  float*  Bias   = (float*)(ws + 966656);    // 1792*4     = 7,168
  unsigned* barc = (unsigned*)(ws + 973824);
  if (ws_size < (size_t)(1 << 20)) return;

  hipFuncSetAttribute((const void*)fused_gru, hipFuncAttributeMaxDynamicSharedMemorySize,
                      SMEM_BYTES);

  pack_w<<<dim3(192), dim3(256), 0, stream>>>(bbWx, bbWh, uWx, spWx,
                                              bbbx, bbbh, ubx, ubh, spbx, spbh,
                                              Bzr, Bh, Bu, Bias, barc);
  fused_gru<<<dim3(GRID), dim3(512), SMEM_BYTES, stream>>>(
      X, Bzr, Bh, Bu, Bias, Wu, Ws, Wp, buv, bsv, bpv, out, barc);
}